// Round 27
// baseline (195.934 us; speedup 1.0000x reference)
//
#include <hip/hip_runtime.h>
#include <float.h>

#define BB 2
#define LL 2048
#define EE 1024
#define HH 16
#define DHD 64
#define WIN 128

typedef __attribute__((ext_vector_type(8))) short short8v;       // 8 u16
typedef __attribute__((ext_vector_type(8))) _Float16 half8v;     // 8 fp16
typedef __attribute__((ext_vector_type(4))) float f32x4;

static __device__ __forceinline__ unsigned short f2h(float f) {
    union { _Float16 h; unsigned short u; } x; x.h = (_Float16)f; return x.u;
}
static __device__ __forceinline__ float h2f_u(unsigned short u) {
    union { unsigned short u; _Float16 h; } x{u}; return (float)x.h;
}
static __device__ __forceinline__ void f2h_split(float f, unsigned short& hi,
                                                 unsigned short& lo) {
    _Float16 h = (_Float16)f;          // RNE
    _Float16 l = (_Float16)(f - (float)h);
    union { _Float16 h; unsigned short u; } uh, ul;
    uh.h = h; ul.h = l;
    hi = uh.u;
    lo = ul.u;
}

// K tiled layout: ktl[bh][t=c/16][plane][g=d/8][c&15][8] -> 1 KB wave reads.
#define KTL_PER_BH   262144            // 128 tiles * 2048 u16
#define KTL_PER_TILE 2048
// V tiled layout: vtl[bh][t=c/32][n=0..63][c&31] -> dense PV fragment reads.
#define VTL_PER_BH   131072            // 64 tiles * 2048 u16
#define VTL_PER_TILE 2048

// ---------------- prep: split x, Wq, Wk into fp16 hi/lo planes -------------
__global__ __launch_bounds__(256) void prep_split(
    const float* __restrict__ x, const float* __restrict__ Wq,
    const float* __restrict__ Wk,
    unsigned short* __restrict__ xh, unsigned short* __restrict__ xl,
    unsigned short* __restrict__ wqh, unsigned short* __restrict__ wql,
    unsigned short* __restrict__ wkh, unsigned short* __restrict__ wkl)
{
    const size_t NX = (size_t)BB * LL * EE;        // 4M
    const size_t NW = (size_t)EE * EE;             // 1M
    const size_t total = NX + 2 * NW;
    const size_t stride = (size_t)gridDim.x * 256 * 4;
    for (size_t i = (size_t)(blockIdx.x * 256 + threadIdx.x) * 4;
         i < total; i += stride) {
        const float* src; unsigned short *dh, *dl; size_t off;
        if (i < NX)            { src = x;  dh = xh;  dl = xl;  off = i; }
        else if (i < NX + NW)  { src = Wq; dh = wqh; dl = wql; off = i - NX; }
        else                   { src = Wk; dh = wkh; dl = wkl; off = i - NX - NW; }
        const float4 v = *(const float4*)(src + off);
        ushort4 h4, l4;
        f2h_split(v.x, h4.x, l4.x);
        f2h_split(v.y, h4.y, l4.y);
        f2h_split(v.z, h4.z, l4.z);
        f2h_split(v.w, h4.w, l4.w);
        *(ushort4*)(dh + off) = h4;
        *(ushort4*)(dl + off) = l4;
    }
}

// ---------------- pack pos_bias + convert Wo -> fp16 (AFTER gemm_qkv) ------
__global__ __launch_bounds__(256) void pack_bias(
    const float* __restrict__ pb, float* __restrict__ pbp,
    float* __restrict__ pb0, const float* __restrict__ Wo,
    unsigned short* __restrict__ woh)
{
    const int r = blockIdx.x;
    int lo_w = (r & ~15) - WIN; if (lo_w < 0) lo_w = 0;
    for (int t = threadIdx.x; t < 272; t += 256) {
        const int c = lo_w + t;
        pbp[(size_t)r * 272 + t] = (c < LL) ? pb[(size_t)r * LL + c] : 0.f;
    }
    if (threadIdx.x == 0) pb0[r] = pb[(size_t)r * LL];
    const size_t i = (size_t)blockIdx.x * 256 + threadIdx.x;
    const float2 v = ((const float2*)Wo)[i];
    ushort2 o2; o2.x = f2h(v.x); o2.y = f2h(v.y);
    ((ushort2*)woh)[i] = o2;
}

// ---------------- merged QKV projection GEMM, BM=64 x BN=64 ----------------
// grid 1024 (16 col x 64 row tiles), ALL blocks uniform: stage A (hi+lo)
// ONCE, compute Q (12 MFMA) + K (12) + V (4) per wave per K-step. Removes
// the duplicate A-hi fetch and the heavy/light block imbalance of r25.
__global__ __launch_bounds__(256, 3) void gemm_qkv(
    const unsigned short* __restrict__ xh, const unsigned short* __restrict__ xl,
    const unsigned short* __restrict__ wqh, const unsigned short* __restrict__ wql,
    const unsigned short* __restrict__ wkh, const unsigned short* __restrict__ wkl,
    const float* __restrict__ Wv,
    const float* __restrict__ bq, const float* __restrict__ bk,
    const float* __restrict__ bv,
    unsigned short* __restrict__ qhi, unsigned short* __restrict__ qlo,
    unsigned short* __restrict__ ktl,
    unsigned short* __restrict__ vtl)
{
    __shared__ unsigned short Ah[64 * 40], Al[64 * 40];       // 5 KB each
    __shared__ unsigned short Bqh[64 * 40], Bql[64 * 40];
    __shared__ unsigned short Bkh[64 * 40], Bkl[64 * 40];
    __shared__ unsigned short Bvh[64 * 40];                   // total 35 KB

    const int bid = blockIdx.x;
    const int col0 = (bid & 15) * 64;
    const int row0 = (bid >> 4) * 64;
    const int tid = threadIdx.x;
    const int w = tid >> 6, lane = tid & 63;
    const int wr = w >> 1, wc = w & 1;          // wave tile: 32 x 32
    const int lr16 = lane & 15, kg = lane >> 4;
    const int ri = tid >> 2, rq = tid & 3;      // 64 rows x 4 k-quads
    const int sbase = ri * 40 + rq * 8;

    const unsigned short* arow_h = xh + (size_t)(row0 + ri) * EE + rq * 8;
    const unsigned short* arow_l = xl + (size_t)(row0 + ri) * EE + rq * 8;
    const unsigned short* bq_h = wqh + (size_t)(col0 + ri) * EE + rq * 8;
    const unsigned short* bq_l = wql + (size_t)(col0 + ri) * EE + rq * 8;
    const unsigned short* bk_h = wkh + (size_t)(col0 + ri) * EE + rq * 8;
    const unsigned short* bk_l = wkl + (size_t)(col0 + ri) * EE + rq * 8;
    const float* vrow = Wv + (size_t)(col0 + ri) * EE + rq * 8;

    f32x4 accQ[2][2], accK[2][2], accV[2][2];
#pragma unroll
    for (int i = 0; i < 2; i++)
#pragma unroll
        for (int j = 0; j < 2; j++) {
            accQ[i][j] = (f32x4){0.f, 0.f, 0.f, 0.f};
            accK[i][j] = (f32x4){0.f, 0.f, 0.f, 0.f};
            accV[i][j] = (f32x4){0.f, 0.f, 0.f, 0.f};
        }

    for (int t = 0; t < EE / 32; t++) {
        const int k0 = t * 32;
        const short8v ra = *(const short8v*)(arow_h + k0);
        const short8v la = *(const short8v*)(arow_l + k0);
        const short8v qb = *(const short8v*)(bq_h + k0);
        const short8v ql = *(const short8v*)(bq_l + k0);
        const short8v kb = *(const short8v*)(bk_h + k0);
        const short8v kl = *(const short8v*)(bk_l + k0);
        const float4 f0 = *(const float4*)(vrow + k0);
        const float4 f1 = *(const float4*)(vrow + k0 + 4);
        unsigned short ub[8];
        ub[0] = f2h(f0.x); ub[1] = f2h(f0.y); ub[2] = f2h(f0.z); ub[3] = f2h(f0.w);
        ub[4] = f2h(f1.x); ub[5] = f2h(f1.y); ub[6] = f2h(f1.z); ub[7] = f2h(f1.w);
        __syncthreads();                     // prev iter reads done
        *(short8v*)&Ah[sbase]  = ra;
        *(short8v*)&Al[sbase]  = la;
        *(short8v*)&Bqh[sbase] = qb;
        *(short8v*)&Bql[sbase] = ql;
        *(short8v*)&Bkh[sbase] = kb;
        *(short8v*)&Bkl[sbase] = kl;
        *(short8v*)&Bvh[sbase] = *(short8v*)&ub[0];
        __syncthreads();                     // writes visible

        half8v afh[2], afl[2], bfh[2], bfl[2];
#pragma unroll
        for (int mr = 0; mr < 2; mr++) {
            const int off = (wr * 32 + mr * 16 + lr16) * 40 + kg * 8;
            afh[mr] = *(const half8v*)&Ah[off];
            afl[mr] = *(const half8v*)&Al[off];
        }
        // ---- Q ----
#pragma unroll
        for (int nr = 0; nr < 2; nr++) {
            const int off = (wc * 32 + nr * 16 + lr16) * 40 + kg * 8;
            bfh[nr] = *(const half8v*)&Bqh[off];
            bfl[nr] = *(const half8v*)&Bql[off];
        }
#pragma unroll
        for (int mr = 0; mr < 2; mr++)
#pragma unroll
            for (int nr = 0; nr < 2; nr++) {
                accQ[mr][nr] = __builtin_amdgcn_mfma_f32_16x16x32_f16(
                    afl[mr], bfh[nr], accQ[mr][nr], 0, 0, 0);
                accQ[mr][nr] = __builtin_amdgcn_mfma_f32_16x16x32_f16(
                    afh[mr], bfl[nr], accQ[mr][nr], 0, 0, 0);
                accQ[mr][nr] = __builtin_amdgcn_mfma_f32_16x16x32_f16(
                    afh[mr], bfh[nr], accQ[mr][nr], 0, 0, 0);
            }
        // ---- K ----
#pragma unroll
        for (int nr = 0; nr < 2; nr++) {
            const int off = (wc * 32 + nr * 16 + lr16) * 40 + kg * 8;
            bfh[nr] = *(const half8v*)&Bkh[off];
            bfl[nr] = *(const half8v*)&Bkl[off];
        }
#pragma unroll
        for (int mr = 0; mr < 2; mr++)
#pragma unroll
            for (int nr = 0; nr < 2; nr++) {
                accK[mr][nr] = __builtin_amdgcn_mfma_f32_16x16x32_f16(
                    afl[mr], bfh[nr], accK[mr][nr], 0, 0, 0);
                accK[mr][nr] = __builtin_amdgcn_mfma_f32_16x16x32_f16(
                    afh[mr], bfl[nr], accK[mr][nr], 0, 0, 0);
                accK[mr][nr] = __builtin_amdgcn_mfma_f32_16x16x32_f16(
                    afh[mr], bfh[nr], accK[mr][nr], 0, 0, 0);
            }
        // ---- V (fp16-hi single term) ----
#pragma unroll
        for (int nr = 0; nr < 2; nr++) {
            const int off = (wc * 32 + nr * 16 + lr16) * 40 + kg * 8;
            bfh[nr] = *(const half8v*)&Bvh[off];
        }
#pragma unroll
        for (int mr = 0; mr < 2; mr++)
#pragma unroll
            for (int nr = 0; nr < 2; nr++)
                accV[mr][nr] = __builtin_amdgcn_mfma_f32_16x16x32_f16(
                    afh[mr], bfh[nr], accV[mr][nr], 0, 0, 0);
    }

    // epilogue: C/D layout col = lane&15, row = (lane>>4)*4 + reg
#pragma unroll
    for (int mr = 0; mr < 2; mr++) {
#pragma unroll
        for (int nr = 0; nr < 2; nr++) {
            const int n = col0 + wc * 32 + nr * 16 + lr16;
            const float bbq = bq[n];
            const float bbk = bk[n];
            const float bbv = bv[n];
#pragma unroll
            for (int j = 0; j < 4; j++) {
                const int m = row0 + wr * 32 + mr * 16 + kg * 4 + j;
                const int bi = m >> 11, l = m & (LL - 1);
                const int hh = n >> 6, d = n & 63;
                const int bhh = bi * HH + hh;
                const size_t o = ((size_t)bhh * LL + l) * DHD + d;
                unsigned short hu, lu;
                f2h_split(accQ[mr][nr][j] + bbq, hu, lu);
                qhi[o] = hu; qlo[o] = lu;
                f2h_split(accK[mr][nr][j] + bbk, hu, lu);
                const size_t ko = (size_t)bhh * KTL_PER_BH +
                                  (size_t)(l >> 4) * KTL_PER_TILE +
                                  (size_t)(d >> 3) * 128 +
                                  (size_t)(l & 15) * 8 + (d & 7);
                ktl[ko] = hu;
                ktl[ko + 1024] = lu;
                const size_t vo = (size_t)bhh * VTL_PER_BH +
                                  (size_t)(l >> 5) * VTL_PER_TILE +
                                  (size_t)d * 32 + (l & 31);
                vtl[vo] = f2h(accV[mr][nr][j] + bbv);
            }
        }
    }
}

// ---------------- MFMA windowed attention (4 waves) + fused row-0 ----------
__global__ __launch_bounds__(256) void attn_mfma(
    const unsigned short* __restrict__ qhi, const unsigned short* __restrict__ qlo,
    const unsigned short* __restrict__ ktl,
    const unsigned short* __restrict__ vtl, const float* __restrict__ pos_bias,
    const float* __restrict__ pbp, const float* __restrict__ pb0,
    unsigned short* __restrict__ attn16)
{
    __shared__ __align__(16) unsigned short Pl[4][16][296];
    __shared__ float s0s[4][16];

    const int bid = blockIdx.x;
    const int tid = threadIdx.x;

    if (bid < 32) {
        // ---- dense row 0 for one head (vectorized, 256 thr) ----
        const int head = bid;
        const int b = head >> 4, h = head & 15;
        float* sc = (float*)&Pl[0][0][0];
        float* red = sc + LL;
        float* qs = red + 256;
        const size_t bh = (size_t)(b * HH + h);
        const size_t bhL = bh * LL;
        const unsigned short* ktb = ktl + bh * KTL_PER_BH;
        const unsigned short* vtb = vtl + bh * VTL_PER_BH;

        if (tid < DHD)
            qs[tid] = h2f_u(qhi[bhL * DHD + tid]) + h2f_u(qlo[bhL * DHD + tid]);
        __syncthreads();

        for (int j = tid; j < LL; j += 256) {
            const unsigned short* tb = ktb + (size_t)(j >> 4) * KTL_PER_TILE +
                                       (size_t)(j & 15) * 8;
            float s = 0.f;
#pragma unroll
            for (int d8 = 0; d8 < 8; d8++) {
                const half8v kh8 = *(const half8v*)(tb + d8 * 128);
                const half8v kl8 = *(const half8v*)(tb + 1024 + d8 * 128);
#pragma unroll
                for (int e = 0; e < 8; e++)
                    s = fmaf(qs[d8 * 8 + e], (float)kh8[e] + (float)kl8[e], s);
            }
            s *= 0.125f;
            sc[j] = (s > 0.f) ? s + pos_bias[j] : -FLT_MAX;
        }
        __syncthreads();

        float m = -FLT_MAX;
        for (int j = tid; j < LL; j += 256) m = fmaxf(m, sc[j]);
        red[tid] = m;
        __syncthreads();
        for (int s = 128; s > 0; s >>= 1) {
            if (tid < s) red[tid] = fmaxf(red[tid], red[tid + s]);
            __syncthreads();
        }
        m = red[0];
        __syncthreads();

        float lsum = 0.f;
        for (int j = tid; j < LL; j += 256) {
            const float p = expf(sc[j] - m);
            sc[j] = p;
            lsum += p;
        }
        red[tid] = lsum;
        __syncthreads();
        for (int s = 128; s > 0; s >>= 1) {
            if (tid < s) red[tid] += red[tid + s];
            __syncthreads();
        }
        const float inv = 1.0f / red[0];
        __syncthreads();

        const int d = tid & 63, part = tid >> 6;
        float a = 0.f;
        for (int j0 = part * 8; j0 < LL; j0 += 32) {
            const half8v v8 = *(const half8v*)(vtb +
                (size_t)(j0 >> 5) * VTL_PER_TILE + (size_t)d * 32 + (j0 & 31));
#pragma unroll
            for (int e = 0; e < 8; e++)
                a = fmaf(sc[j0 + e], (float)v8[e], a);
        }
        red[tid] = a;
        __syncthreads();
        if (tid < 64) {
            const float tot = (red[tid] + red[tid + 64]) +
                              (red[tid + 128] + red[tid + 192]);
            attn16[(size_t)b * LL * EE + h * DHD + tid] = f2h(tot * inv);
        }
        return;
    }

    // ---- windowed path ----
    const int vbid = bid - 32;
    const int head = vbid & 31, chunk = vbid >> 5;   // XCD-local: head%8 fixed
    const int b = head >> 4, h = head & 15;
    const int w = tid >> 6, lane = tid & 63;
    const int lq = lane & 15, kg = lane >> 4;
    const int r0w = chunk * 64 + w * 16;

    const size_t bh = (size_t)(b * HH + h);
    const size_t bhL = bh * LL;
    const unsigned short* qhb = qhi + (bhL + r0w) * DHD;
    const unsigned short* qlb = qlo + (bhL + r0w) * DHD;
    const unsigned short* ktb = ktl + bh * KTL_PER_BH;
    const unsigned short* vtb = vtl + bh * VTL_PER_BH;

    int lo = r0w - WIN; if (lo < 0) lo = 0;
    int hi = r0w + 15 + WIN; if (hi > LL - 1) hi = LL - 1;
    const bool has0 = (lo > 0);
    const int t0 = lo >> 4;                          // lo is a multiple of 16

    // zero P pad cols [272,296)
    for (int idx = lane; idx < 96; idx += 64) {
        const int rr = idx / 6, cc = 272 + (idx % 6) * 4;
        *(unsigned long long*)&Pl[w][rr][cc] = 0ull;
    }

    half8v qfh[2], qfl[2];
#pragma unroll
    for (int kf = 0; kf < 2; kf++) {
        const int off = lq * DHD + kf * 32 + kg * 8;
        qfh[kf] = *(const half8v*)(qhb + off);
        qfl[kf] = *(const half8v*)(qlb + off);
    }

    // ---- QK^T: 17 frags, tiled-K contiguous loads ----
    f32x4 acc[17];
#pragma unroll
    for (int f = 0; f < 17; f++) {
        int tt = t0 + f;
        if (tt > 127) tt = 127;                  // OOB tiles masked later
        const unsigned short* tb = ktb + (size_t)tt * KTL_PER_TILE;
        const int lofs = kg * 128 + lq * 8;
        const half8v b0h = *(const half8v*)(tb + lofs);
        const half8v b1h = *(const half8v*)(tb + 512 + lofs);
        const half8v b0l = *(const half8v*)(tb + 1024 + lofs);
        const half8v b1l = *(const half8v*)(tb + 1536 + lofs);
        f32x4 a = (f32x4){0.f, 0.f, 0.f, 0.f};
        a = __builtin_amdgcn_mfma_f32_16x16x32_f16(qfl[0], b0h, a, 0, 0, 0);
        a = __builtin_amdgcn_mfma_f32_16x16x32_f16(qfh[0], b0l, a, 0, 0, 0);
        a = __builtin_amdgcn_mfma_f32_16x16x32_f16(qfh[0], b0h, a, 0, 0, 0);
        a = __builtin_amdgcn_mfma_f32_16x16x32_f16(qfl[1], b1h, a, 0, 0, 0);
        a = __builtin_amdgcn_mfma_f32_16x16x32_f16(qfh[1], b1l, a, 0, 0, 0);
        a = __builtin_amdgcn_mfma_f32_16x16x32_f16(qfh[1], b1h, a, 0, 0, 0);
        acc[f] = a;
    }

    // ---- col-0 scalar dot ----
    float sc0 = -FLT_MAX;
    if (has0) {
        float part = 0.f;
        const int rowoff = lq * DHD;
#pragma unroll
        for (int e = 0; e < 16; e++) {
            const int d = kg * 16 + e;
            const float qv = h2f_u(qhb[rowoff + d]) + h2f_u(qlb[rowoff + d]);
            const int kofs = (d >> 3) * 128 + (d & 7);
            const float kv = h2f_u(ktb[kofs]) + h2f_u(ktb[1024 + kofs]);
            part = fmaf(qv, kv, part);
        }
        part += __shfl_xor(part, 16);
        part += __shfl_xor(part, 32);
        const float s = part * 0.125f;
        sc0 = (s > 0.f) ? s + pb0[r0w + lq] : -FLT_MAX;
    }
    if (lane < 16) s0s[w][lq] = sc0;

    // ---- gate + bias (C-layout: col = lane&15, row = kg*4+rg) ----
#pragma unroll
    for (int f = 0; f < 17; f++) {
        const int c = lo + f * 16 + lq;
        const bool cok = (c <= hi);
        f32x4 s4 = acc[f];
#pragma unroll
        for (int rg = 0; rg < 4; rg++) {
            const int r = r0w + kg * 4 + rg;
            const bool allowed = cok &&
                ((c == 0) || ((c >= r - WIN) && (c <= r + WIN)));
            const float s = s4[rg] * 0.125f;
            float sc = -FLT_MAX;
            if (allowed && s > 0.f)
                sc = s + pbp[(size_t)r * 272 + f * 16 + lq];
            s4[rg] = sc;
        }
        acc[f] = s4;
    }

    // ---- softmax (in-register, 16-lane butterflies) ----
    float s0r[4], mx[4];
#pragma unroll
    for (int rg = 0; rg < 4; rg++) {
        s0r[rg] = s0s[w][kg * 4 + rg];
        float m = s0r[rg];
#pragma unroll
        for (int f = 0; f < 17; f++) m = fmaxf(m, acc[f][rg]);
        m = fmaxf(m, __shfl_xor(m, 1));
        m = fmaxf(m, __shfl_xor(m, 2));
        m = fmaxf(m, __shfl_xor(m, 4));
        m = fmaxf(m, __shfl_xor(m, 8));
        mx[rg] = m;
    }

    float sum0 = 0.f, sum1 = 0.f, sum2 = 0.f, sum3 = 0.f;
#pragma unroll
    for (int f = 0; f < 17; f++) {
        const float p0_ = __expf(acc[f][0] - mx[0]); sum0 += p0_;
        const float p1_ = __expf(acc[f][1] - mx[1]); sum1 += p1_;
        const float p2_ = __expf(acc[f][2] - mx[2]); sum2 += p2_;
        const float p3_ = __expf(acc[f][3] - mx[3]); sum3 += p3_;
        Pl[w][kg * 4 + 0][f * 16 + lq] = f2h(p0_);
        Pl[w][kg * 4 + 1][f * 16 + lq] = f2h(p1_);
        Pl[w][kg * 4 + 2][f * 16 + lq] = f2h(p2_);
        Pl[w][kg * 4 + 3][f * 16 + lq] = f2h(p3_);
    }

    float inv[4], p0v[4];
    float sums[4] = {sum0, sum1, sum2, sum3};
#pragma unroll
    for (int rg = 0; rg < 4; rg++) {
        float s = sums[rg];
        s += __shfl_xor(s, 1);
        s += __shfl_xor(s, 2);
        s += __shfl_xor(s, 4);
        s += __shfl_xor(s, 8);
        const float p0 = has0 ? __expf(s0r[rg] - mx[rg]) : 0.f;
        p0v[rg] = p0;
        inv[rg] = 1.0f / (s + p0);
    }

    // ---- PV: A = P (LDS fp16), B = V^T tiled (dense wave reads) ----
    f32x4 pacc[4];
#pragma unroll
    for (int nf = 0; nf < 4; nf++) pacc[nf] = (f32x4){0.f, 0.f, 0.f, 0.f};
#pragma unroll
    for (int kf = 0; kf < 9; kf++) {
        const half8v pa = *(const half8v*)&Pl[w][lq][kf * 32 + kg * 8];
        int c0 = lo + kf * 32 + kg * 8;
        if (c0 > LL - 8) c0 = LL - 8;       // clamped spans have P==0
        const size_t vbase = (size_t)(c0 >> 5) * VTL_PER_TILE + (c0 & 31);
#pragma unroll
        for (int nf = 0; nf < 4; nf++) {
            const half8v vb =
                *(const half8v*)(vtb + vbase + (size_t)(nf * 16 + lq) * 32);
            pacc[nf] = __builtin_amdgcn_mfma_f32_16x16x32_f16(
                pa, vb, pacc[nf], 0, 0, 0);
        }
    }

    // ---- epilogue ----
#pragma unroll
    for (int nf = 0; nf < 4; nf++) {
        const int n = nf * 16 + lq;
        const float v0 = has0 ? h2f_u(vtb[(size_t)n * 32]) : 0.f;
#pragma unroll
        for (int rg = 0; rg < 4; rg++) {
            const int r = r0w + kg * 4 + rg;
            const float o = (pacc[nf][rg] + p0v[rg] * v0) * inv[rg];
            if (r != 0)
                attn16[((size_t)(b * LL + r)) * EE + h * DHD + n] = f2h(o);
        }
    }
}

// ---------------- out-proj: fp16 x fp16 MFMA, pipelined, f32 out -----------
__global__ __launch_bounds__(256) void gemm_o(
    const unsigned short* __restrict__ attn16, const unsigned short* __restrict__ woh,
    const float* __restrict__ bo, float* __restrict__ out)
{
    __shared__ unsigned short Ah[128 * 40], Bh[128 * 40];

    const int tid = threadIdx.x;
    const int w = tid >> 6, lane = tid & 63;
    const int wr = w >> 1, wc = w & 1;
    const int lr16 = lane & 15, kg = lane >> 4;
    const int row0 = blockIdx.y * 128, col0 = blockIdx.x * 128;
    const int srow = tid >> 1, shalf = tid & 1;
    const int sbase = srow * 40 + shalf * 16;

    const unsigned short* arow = attn16 + (size_t)(row0 + srow) * EE + shalf * 16;
    const unsigned short* brow = woh + (size_t)(col0 + srow) * EE + shalf * 16;

    f32x4 acc[4][4];
#pragma unroll
    for (int i = 0; i < 4; i++)
#pragma unroll
        for (int j = 0; j < 4; j++) acc[i][j] = (f32x4){0.f, 0.f, 0.f, 0.f};

    short8v ra0 = *(const short8v*)(arow + 0);
    short8v ra1 = *(const short8v*)(arow + 8);
    short8v rb0 = *(const short8v*)(brow + 0);
    short8v rb1 = *(const short8v*)(brow + 8);

    for (int t = 0; t < EE / 32; t++) {
        __syncthreads();
        *(short8v*)&Ah[sbase + 0] = ra0;
        *(short8v*)&Ah[sbase + 8] = ra1;
        *(short8v*)&Bh[sbase + 0] = rb0;
        *(short8v*)&Bh[sbase + 8] = rb1;
        __syncthreads();

        if (t + 1 < EE / 32) {
            const int k0 = (t + 1) * 32;
            ra0 = *(const short8v*)(arow + k0);
            ra1 = *(const short8v*)(arow + k0 + 8);
            rb0 = *(const short8v*)(brow + k0);
            rb1 = *(const short8v*)(brow + k0 + 8);
        }

        half8v af[4], bf[4];
#pragma unroll
        for (int mr = 0; mr < 4; mr++)
            af[mr] = *(const half8v*)&Ah[(wr*64 + mr*16 + lr16)*40 + kg*8];
#pragma unroll
        for (int nr = 0; nr < 4; nr++)
            bf[nr] = *(const half8v*)&Bh[(wc*64 + nr*16 + lr16)*40 + kg*8];
#pragma unroll
        for (int mr = 0; mr < 4; mr++)
#pragma unroll
            for (int nr = 0; nr < 4; nr++)
                acc[mr][nr] = __builtin_amdgcn_mfma_f32_16x16x32_f16(
                    af[mr], bf[nr], acc[mr][nr], 0, 0, 0);
    }

#pragma unroll
    for (int mr = 0; mr < 4; mr++) {
#pragma unroll
        for (int nr = 0; nr < 4; nr++) {
            const int n = col0 + wc * 64 + nr * 16 + lr16;
            const float bb = bo[n];
#pragma unroll
            for (int j = 0; j < 4; j++) {
                const int m = row0 + wr * 64 + mr * 16 + kg * 4 + j;
                out[(size_t)m * EE + n] = acc[mr][nr][j] + bb;
            }
        }
    }
}

extern "C" void kernel_launch(void* const* d_in, const int* in_sizes, int n_in,
                              void* d_out, int out_size, void* d_ws, size_t ws_size,
                              hipStream_t stream) {
    const float* x        = (const float*)d_in[0];
    const float* pos_bias = (const float*)d_in[1];
    const float* Wq = (const float*)d_in[2];
    const float* bq = (const float*)d_in[3];
    const float* Wk = (const float*)d_in[4];
    const float* bk = (const float*)d_in[5];
    const float* Wv = (const float*)d_in[6];
    const float* bv = (const float*)d_in[7];
    const float* Wo = (const float*)d_in[8];
    const float* bo = (const float*)d_in[9];
    float* out = (float*)d_out;

    const size_t M1 = (size_t)1024 * 1024;         // 1M u16 units
    unsigned short* u = (unsigned short*)d_ws;
    unsigned short* xh  = u;                        // 4M
    unsigned short* xl  = u + 4 * M1;               // 4M (dead after gemm_qkv)
    unsigned short* wqh = u + 8 * M1;               // 1M each
    unsigned short* wql = u + 9 * M1;
    unsigned short* wkh = u + 10 * M1;
    unsigned short* wkl = u + 11 * M1;
    unsigned short* qhi = u + 12 * M1;              // 4M each
    unsigned short* qlo = u + 16 * M1;
    unsigned short* ktl = u + 20 * M1;              // 8M (tiled K hi+lo)
    unsigned short* vtl = u + 28 * M1;              // 4M (tiled V) -> 32M u16
    unsigned short* attn16 = xh;                    // reuse (xh dead post-QKV)
    float* pbp = (float*)(u + 4 * M1);              // reuse xl AFTER gemm_qkv
    float* pb0 = pbp + (size_t)2048 * 272;          // + 2048 f32
    unsigned short* woh = u + 7 * M1;               // xl region tail: 1M u16

    prep_split<<<dim3(2048), 256, 0, stream>>>(x, Wq, Wk, xh, xl,
                                               wqh, wql, wkh, wkl);
    gemm_qkv<<<dim3(1024), 256, 0, stream>>>(xh, xl, wqh, wql, wkh, wkl,
                                             Wv, bq, bk, bv,
                                             qhi, qlo, ktl, vtl);
    pack_bias<<<dim3(2048), 256, 0, stream>>>(pos_bias, pbp, pb0, Wo, woh);
    attn_mfma<<<dim3(1056), 256, 0, stream>>>(qhi, qlo, ktl, vtl,
                                              pos_bias, pbp, pb0, attn16);
    gemm_o<<<dim3(8, 32), 256, 0, stream>>>(attn16, woh, bo, out);
}

// Round 28
// 182.324 us; speedup vs baseline: 1.0746x; 1.0746x over previous
//
#include <hip/hip_runtime.h>
#include <float.h>

#define BB 2
#define LL 2048
#define EE 1024
#define HH 16
#define DHD 64
#define WIN 128

typedef __attribute__((ext_vector_type(8))) short short8v;       // 8 u16
typedef __attribute__((ext_vector_type(8))) _Float16 half8v;     // 8 fp16
typedef __attribute__((ext_vector_type(4))) float f32x4;

static __device__ __forceinline__ unsigned short f2h(float f) {
    union { _Float16 h; unsigned short u; } x; x.h = (_Float16)f; return x.u;
}
static __device__ __forceinline__ float h2f_u(unsigned short u) {
    union { unsigned short u; _Float16 h; } x{u}; return (float)x.h;
}
static __device__ __forceinline__ void f2h_split(float f, unsigned short& hi,
                                                 unsigned short& lo) {
    _Float16 h = (_Float16)f;          // RNE
    _Float16 l = (_Float16)(f - (float)h);
    union { _Float16 h; unsigned short u; } uh, ul;
    uh.h = h; ul.h = l;
    hi = uh.u;
    lo = ul.u;
}

// K tiled layout: ktl[bh][t=c/16][plane][g=d/8][c&15][8] -> 1 KB wave reads.
#define KTL_PER_BH   262144            // 128 tiles * 2048 u16
#define KTL_PER_TILE 2048
// V tiled layout: vtl[bh][t=c/32][n=0..63][c&31] -> dense PV fragment reads.
#define VTL_PER_BH   131072            // 64 tiles * 2048 u16
#define VTL_PER_TILE 2048

// ---------------- prep: split x, Wq, Wk into fp16 hi/lo planes -------------
__global__ __launch_bounds__(256) void prep_split(
    const float* __restrict__ x, const float* __restrict__ Wq,
    const float* __restrict__ Wk,
    unsigned short* __restrict__ xh, unsigned short* __restrict__ xl,
    unsigned short* __restrict__ wqh, unsigned short* __restrict__ wql,
    unsigned short* __restrict__ wkh, unsigned short* __restrict__ wkl)
{
    const size_t NX = (size_t)BB * LL * EE;        // 4M
    const size_t NW = (size_t)EE * EE;             // 1M
    const size_t total = NX + 2 * NW;
    const size_t stride = (size_t)gridDim.x * 256 * 4;
    for (size_t i = (size_t)(blockIdx.x * 256 + threadIdx.x) * 4;
         i < total; i += stride) {
        const float* src; unsigned short *dh, *dl; size_t off;
        if (i < NX)            { src = x;  dh = xh;  dl = xl;  off = i; }
        else if (i < NX + NW)  { src = Wq; dh = wqh; dl = wql; off = i - NX; }
        else                   { src = Wk; dh = wkh; dl = wkl; off = i - NX - NW; }
        const float4 v = *(const float4*)(src + off);
        ushort4 h4, l4;
        f2h_split(v.x, h4.x, l4.x);
        f2h_split(v.y, h4.y, l4.y);
        f2h_split(v.z, h4.z, l4.z);
        f2h_split(v.w, h4.w, l4.w);
        *(ushort4*)(dh + off) = h4;
        *(ushort4*)(dl + off) = l4;
    }
}

// ---------------- pack pos_bias + convert Wo -> fp16 (AFTER gemm_qkv) ------
__global__ __launch_bounds__(256) void pack_bias(
    const float* __restrict__ pb, float* __restrict__ pbp,
    float* __restrict__ pb0, const float* __restrict__ Wo,
    unsigned short* __restrict__ woh)
{
    const int r = blockIdx.x;
    int lo_w = (r & ~15) - WIN; if (lo_w < 0) lo_w = 0;
    for (int t = threadIdx.x; t < 272; t += 256) {
        const int c = lo_w + t;
        pbp[(size_t)r * 272 + t] = (c < LL) ? pb[(size_t)r * LL + c] : 0.f;
    }
    if (threadIdx.x == 0) pb0[r] = pb[(size_t)r * LL];
    const size_t i = (size_t)blockIdx.x * 256 + threadIdx.x;
    const float2 v = ((const float2*)Wo)[i];
    ushort2 o2; o2.x = f2h(v.x); o2.y = f2h(v.y);
    ((ushort2*)woh)[i] = o2;
}

// ---------------- fused QK+V projection GEMM, BN=64 for occupancy ----------
// K -> tiled ktl; V -> tiled vtl (r26 best-measured configuration).
__global__ __launch_bounds__(256, 4) void gemm_qkv(
    const unsigned short* __restrict__ xh, const unsigned short* __restrict__ xl,
    const unsigned short* __restrict__ wqh, const unsigned short* __restrict__ wql,
    const unsigned short* __restrict__ wkh, const unsigned short* __restrict__ wkl,
    const float* __restrict__ Wv,
    const float* __restrict__ bq, const float* __restrict__ bk,
    const float* __restrict__ bv,
    unsigned short* __restrict__ qhi, unsigned short* __restrict__ qlo,
    unsigned short* __restrict__ ktl,
    unsigned short* __restrict__ vtl)
{
    __shared__ unsigned short Ah[128 * 40], Al[128 * 40];     // 10 KB each
    __shared__ unsigned short Bqh[64 * 40], Bql[64 * 40];     // 5 KB each
    __shared__ unsigned short Bkh[64 * 40], Bkl[64 * 40];     // total 40 KB

    const int bid = blockIdx.x;
    const bool isqk = bid < 512;
    const int tile = isqk ? bid : bid - 512;
    const int col0 = (tile & 15) * 64;
    const int row0 = (tile >> 4) * 128;
    const int tid = threadIdx.x;
    const int w = tid >> 6, lane = tid & 63;
    const int wr = w >> 1, wc = w & 1;          // wave tile: 64 x 32
    const int lr16 = lane & 15, kg = lane >> 4;
    const int arow_i = tid >> 1, ahalf = tid & 1;    // A: 128 rows x 2 halves
    const int sbaseA = arow_i * 40 + ahalf * 16;
    const int brow_i = tid >> 2, bquad = tid & 3;    // B: 64 rows x 4 quads
    const int sbaseB = brow_i * 40 + bquad * 8;

    const unsigned short* arow_h = xh + (size_t)(row0 + arow_i) * EE + ahalf * 16;
    const unsigned short* arow_l = xl + (size_t)(row0 + arow_i) * EE + ahalf * 16;
    const unsigned short* bq_h = wqh + (size_t)(col0 + brow_i) * EE + bquad * 8;
    const unsigned short* bq_l = wql + (size_t)(col0 + brow_i) * EE + bquad * 8;
    const unsigned short* bk_h = wkh + (size_t)(col0 + brow_i) * EE + bquad * 8;
    const unsigned short* bk_l = wkl + (size_t)(col0 + brow_i) * EE + bquad * 8;
    const float* vrow = Wv + (size_t)(col0 + brow_i) * EE + bquad * 8;

    if (isqk) {
        f32x4 accQ[4][2], accK[4][2];
#pragma unroll
        for (int i = 0; i < 4; i++)
#pragma unroll
            for (int j = 0; j < 2; j++) {
                accQ[i][j] = (f32x4){0.f, 0.f, 0.f, 0.f};
                accK[i][j] = (f32x4){0.f, 0.f, 0.f, 0.f};
            }

        for (int t = 0; t < EE / 32; t++) {
            const int k0 = t * 32;
            const short8v ra0 = *(const short8v*)(arow_h + k0);
            const short8v ra1 = *(const short8v*)(arow_h + k0 + 8);
            const short8v la0 = *(const short8v*)(arow_l + k0);
            const short8v la1 = *(const short8v*)(arow_l + k0 + 8);
            const short8v qb = *(const short8v*)(bq_h + k0);
            const short8v ql = *(const short8v*)(bq_l + k0);
            const short8v kb = *(const short8v*)(bk_h + k0);
            const short8v kl = *(const short8v*)(bk_l + k0);
            __syncthreads();                     // prev iter reads done
            *(short8v*)&Ah[sbaseA + 0] = ra0;
            *(short8v*)&Ah[sbaseA + 8] = ra1;
            *(short8v*)&Al[sbaseA + 0] = la0;
            *(short8v*)&Al[sbaseA + 8] = la1;
            *(short8v*)&Bqh[sbaseB] = qb;
            *(short8v*)&Bql[sbaseB] = ql;
            *(short8v*)&Bkh[sbaseB] = kb;
            *(short8v*)&Bkl[sbaseB] = kl;
            __syncthreads();                     // writes visible

            half8v afh[4], afl[4], bfh[2], bfl[2];
#pragma unroll
            for (int mr = 0; mr < 4; mr++) {
                const int off = (wr * 64 + mr * 16 + lr16) * 40 + kg * 8;
                afh[mr] = *(const half8v*)&Ah[off];
                afl[mr] = *(const half8v*)&Al[off];
            }
            // ---- Q ----
#pragma unroll
            for (int nr = 0; nr < 2; nr++) {
                const int off = (wc * 32 + nr * 16 + lr16) * 40 + kg * 8;
                bfh[nr] = *(const half8v*)&Bqh[off];
                bfl[nr] = *(const half8v*)&Bql[off];
            }
#pragma unroll
            for (int mr = 0; mr < 4; mr++)
#pragma unroll
                for (int nr = 0; nr < 2; nr++) {
                    accQ[mr][nr] = __builtin_amdgcn_mfma_f32_16x16x32_f16(
                        afl[mr], bfh[nr], accQ[mr][nr], 0, 0, 0);
                    accQ[mr][nr] = __builtin_amdgcn_mfma_f32_16x16x32_f16(
                        afh[mr], bfl[nr], accQ[mr][nr], 0, 0, 0);
                    accQ[mr][nr] = __builtin_amdgcn_mfma_f32_16x16x32_f16(
                        afh[mr], bfh[nr], accQ[mr][nr], 0, 0, 0);
                }
            // ---- K ----
#pragma unroll
            for (int nr = 0; nr < 2; nr++) {
                const int off = (wc * 32 + nr * 16 + lr16) * 40 + kg * 8;
                bfh[nr] = *(const half8v*)&Bkh[off];
                bfl[nr] = *(const half8v*)&Bkl[off];
            }
#pragma unroll
            for (int mr = 0; mr < 4; mr++)
#pragma unroll
                for (int nr = 0; nr < 2; nr++) {
                    accK[mr][nr] = __builtin_amdgcn_mfma_f32_16x16x32_f16(
                        afl[mr], bfh[nr], accK[mr][nr], 0, 0, 0);
                    accK[mr][nr] = __builtin_amdgcn_mfma_f32_16x16x32_f16(
                        afh[mr], bfl[nr], accK[mr][nr], 0, 0, 0);
                    accK[mr][nr] = __builtin_amdgcn_mfma_f32_16x16x32_f16(
                        afh[mr], bfh[nr], accK[mr][nr], 0, 0, 0);
                }
        }

        // epilogue: C/D layout col = lane&15, row = (lane>>4)*4 + reg
#pragma unroll
        for (int mr = 0; mr < 4; mr++) {
#pragma unroll
            for (int nr = 0; nr < 2; nr++) {
                const int n = col0 + wc * 32 + nr * 16 + lr16;
                const float bbq = bq[n];
                const float bbk = bk[n];
#pragma unroll
                for (int j = 0; j < 4; j++) {
                    const int m = row0 + wr * 64 + mr * 16 + kg * 4 + j;
                    const int bi = m >> 11, l = m & (LL - 1);
                    const int hh = n >> 6, d = n & 63;
                    const int bhh = bi * HH + hh;
                    const size_t o = ((size_t)bhh * LL + l) * DHD + d;
                    unsigned short hu, lu;
                    f2h_split(accQ[mr][nr][j] + bbq, hu, lu);
                    qhi[o] = hu; qlo[o] = lu;
                    f2h_split(accK[mr][nr][j] + bbk, hu, lu);
                    const size_t ko = (size_t)bhh * KTL_PER_BH +
                                      (size_t)(l >> 4) * KTL_PER_TILE +
                                      (size_t)(d >> 3) * 128 +
                                      (size_t)(l & 15) * 8 + (d & 7);
                    ktl[ko] = hu;
                    ktl[ko + 1024] = lu;
                }
            }
        }
    } else {
        // ---- V regime: fp16-hi single MFMA ----
        f32x4 acc[4][2];
#pragma unroll
        for (int i = 0; i < 4; i++)
#pragma unroll
            for (int j = 0; j < 2; j++) acc[i][j] = (f32x4){0.f, 0.f, 0.f, 0.f};

        for (int t = 0; t < EE / 32; t++) {
            const int k0 = t * 32;
            const short8v ra0 = *(const short8v*)(arow_h + k0);
            const short8v ra1 = *(const short8v*)(arow_h + k0 + 8);
            const float4 f0 = *(const float4*)(vrow + k0);
            const float4 f1 = *(const float4*)(vrow + k0 + 4);
            unsigned short ub[8];
            ub[0] = f2h(f0.x); ub[1] = f2h(f0.y); ub[2] = f2h(f0.z); ub[3] = f2h(f0.w);
            ub[4] = f2h(f1.x); ub[5] = f2h(f1.y); ub[6] = f2h(f1.z); ub[7] = f2h(f1.w);
            __syncthreads();
            *(short8v*)&Ah[sbaseA + 0] = ra0;
            *(short8v*)&Ah[sbaseA + 8] = ra1;
            *(short8v*)&Bqh[sbaseB] = *(short8v*)&ub[0];
            __syncthreads();

            half8v af[4], bf[2];
#pragma unroll
            for (int mr = 0; mr < 4; mr++)
                af[mr] = *(const half8v*)&Ah[(wr*64 + mr*16 + lr16)*40 + kg*8];
#pragma unroll
            for (int nr = 0; nr < 2; nr++)
                bf[nr] = *(const half8v*)&Bqh[(wc*32 + nr*16 + lr16)*40 + kg*8];
#pragma unroll
            for (int mr = 0; mr < 4; mr++)
#pragma unroll
                for (int nr = 0; nr < 2; nr++)
                    acc[mr][nr] = __builtin_amdgcn_mfma_f32_16x16x32_f16(
                        af[mr], bf[nr], acc[mr][nr], 0, 0, 0);
        }

#pragma unroll
        for (int mr = 0; mr < 4; mr++) {
#pragma unroll
            for (int nr = 0; nr < 2; nr++) {
                const int n = col0 + wc * 32 + nr * 16 + lr16;
                const float bb = bv[n];
#pragma unroll
                for (int j = 0; j < 4; j++) {
                    const int m = row0 + wr * 64 + mr * 16 + kg * 4 + j;
                    const float val = acc[mr][nr][j] + bb;
                    const int bi = m >> 11, l = m & (LL - 1);
                    const int hh = n >> 6, d = n & 63;
                    const size_t vo = (size_t)(bi * HH + hh) * VTL_PER_BH +
                                      (size_t)(l >> 5) * VTL_PER_TILE +
                                      (size_t)d * 32 + (l & 31);
                    vtl[vo] = f2h(val);
                }
            }
        }
    }
}

// ---------------- MFMA windowed attention (4 waves) + fused row-0 ----------
// K and V both read from tiled layouts -> dense wave loads.
__global__ __launch_bounds__(256) void attn_mfma(
    const unsigned short* __restrict__ qhi, const unsigned short* __restrict__ qlo,
    const unsigned short* __restrict__ ktl,
    const unsigned short* __restrict__ vtl, const float* __restrict__ pos_bias,
    const float* __restrict__ pbp, const float* __restrict__ pb0,
    unsigned short* __restrict__ attn16)
{
    __shared__ __align__(16) unsigned short Pl[4][16][296];
    __shared__ float s0s[4][16];

    const int bid = blockIdx.x;
    const int tid = threadIdx.x;

    if (bid < 32) {
        // ---- dense row 0 for one head (vectorized, 256 thr) ----
        const int head = bid;
        const int b = head >> 4, h = head & 15;
        float* sc = (float*)&Pl[0][0][0];
        float* red = sc + LL;
        float* qs = red + 256;
        const size_t bh = (size_t)(b * HH + h);
        const size_t bhL = bh * LL;
        const unsigned short* ktb = ktl + bh * KTL_PER_BH;
        const unsigned short* vtb = vtl + bh * VTL_PER_BH;

        if (tid < DHD)
            qs[tid] = h2f_u(qhi[bhL * DHD + tid]) + h2f_u(qlo[bhL * DHD + tid]);
        __syncthreads();

        for (int j = tid; j < LL; j += 256) {
            const unsigned short* tb = ktb + (size_t)(j >> 4) * KTL_PER_TILE +
                                       (size_t)(j & 15) * 8;
            float s = 0.f;
#pragma unroll
            for (int d8 = 0; d8 < 8; d8++) {
                const half8v kh8 = *(const half8v*)(tb + d8 * 128);
                const half8v kl8 = *(const half8v*)(tb + 1024 + d8 * 128);
#pragma unroll
                for (int e = 0; e < 8; e++)
                    s = fmaf(qs[d8 * 8 + e], (float)kh8[e] + (float)kl8[e], s);
            }
            s *= 0.125f;
            sc[j] = (s > 0.f) ? s + pos_bias[j] : -FLT_MAX;
        }
        __syncthreads();

        float m = -FLT_MAX;
        for (int j = tid; j < LL; j += 256) m = fmaxf(m, sc[j]);
        red[tid] = m;
        __syncthreads();
        for (int s = 128; s > 0; s >>= 1) {
            if (tid < s) red[tid] = fmaxf(red[tid], red[tid + s]);
            __syncthreads();
        }
        m = red[0];
        __syncthreads();

        float lsum = 0.f;
        for (int j = tid; j < LL; j += 256) {
            const float p = expf(sc[j] - m);
            sc[j] = p;
            lsum += p;
        }
        red[tid] = lsum;
        __syncthreads();
        for (int s = 128; s > 0; s >>= 1) {
            if (tid < s) red[tid] += red[tid + s];
            __syncthreads();
        }
        const float inv = 1.0f / red[0];
        __syncthreads();

        const int d = tid & 63, part = tid >> 6;
        float a = 0.f;
        for (int j0 = part * 8; j0 < LL; j0 += 32) {
            const half8v v8 = *(const half8v*)(vtb +
                (size_t)(j0 >> 5) * VTL_PER_TILE + (size_t)d * 32 + (j0 & 31));
#pragma unroll
            for (int e = 0; e < 8; e++)
                a = fmaf(sc[j0 + e], (float)v8[e], a);
        }
        red[tid] = a;
        __syncthreads();
        if (tid < 64) {
            const float tot = (red[tid] + red[tid + 64]) +
                              (red[tid + 128] + red[tid + 192]);
            attn16[(size_t)b * LL * EE + h * DHD + tid] = f2h(tot * inv);
        }
        return;
    }

    // ---- windowed path ----
    const int vbid = bid - 32;
    const int head = vbid & 31, chunk = vbid >> 5;   // XCD-local: head%8 fixed
    const int b = head >> 4, h = head & 15;
    const int w = tid >> 6, lane = tid & 63;
    const int lq = lane & 15, kg = lane >> 4;
    const int r0w = chunk * 64 + w * 16;

    const size_t bh = (size_t)(b * HH + h);
    const size_t bhL = bh * LL;
    const unsigned short* qhb = qhi + (bhL + r0w) * DHD;
    const unsigned short* qlb = qlo + (bhL + r0w) * DHD;
    const unsigned short* ktb = ktl + bh * KTL_PER_BH;
    const unsigned short* vtb = vtl + bh * VTL_PER_BH;

    int lo = r0w - WIN; if (lo < 0) lo = 0;
    int hi = r0w + 15 + WIN; if (hi > LL - 1) hi = LL - 1;
    const bool has0 = (lo > 0);
    const int t0 = lo >> 4;                          // lo is a multiple of 16

    // zero P pad cols [272,296)
    for (int idx = lane; idx < 96; idx += 64) {
        const int rr = idx / 6, cc = 272 + (idx % 6) * 4;
        *(unsigned long long*)&Pl[w][rr][cc] = 0ull;
    }

    half8v qfh[2], qfl[2];
#pragma unroll
    for (int kf = 0; kf < 2; kf++) {
        const int off = lq * DHD + kf * 32 + kg * 8;
        qfh[kf] = *(const half8v*)(qhb + off);
        qfl[kf] = *(const half8v*)(qlb + off);
    }

    // ---- QK^T: 17 frags, tiled-K contiguous loads ----
    f32x4 acc[17];
#pragma unroll
    for (int f = 0; f < 17; f++) {
        int tt = t0 + f;
        if (tt > 127) tt = 127;                  // OOB tiles masked later
        const unsigned short* tb = ktb + (size_t)tt * KTL_PER_TILE;
        const int lofs = kg * 128 + lq * 8;
        const half8v b0h = *(const half8v*)(tb + lofs);
        const half8v b1h = *(const half8v*)(tb + 512 + lofs);
        const half8v b0l = *(const half8v*)(tb + 1024 + lofs);
        const half8v b1l = *(const half8v*)(tb + 1536 + lofs);
        f32x4 a = (f32x4){0.f, 0.f, 0.f, 0.f};
        a = __builtin_amdgcn_mfma_f32_16x16x32_f16(qfl[0], b0h, a, 0, 0, 0);
        a = __builtin_amdgcn_mfma_f32_16x16x32_f16(qfh[0], b0l, a, 0, 0, 0);
        a = __builtin_amdgcn_mfma_f32_16x16x32_f16(qfh[0], b0h, a, 0, 0, 0);
        a = __builtin_amdgcn_mfma_f32_16x16x32_f16(qfl[1], b1h, a, 0, 0, 0);
        a = __builtin_amdgcn_mfma_f32_16x16x32_f16(qfh[1], b1l, a, 0, 0, 0);
        a = __builtin_amdgcn_mfma_f32_16x16x32_f16(qfh[1], b1h, a, 0, 0, 0);
        acc[f] = a;
    }

    // ---- col-0 scalar dot ----
    float sc0 = -FLT_MAX;
    if (has0) {
        float part = 0.f;
        const int rowoff = lq * DHD;
#pragma unroll
        for (int e = 0; e < 16; e++) {
            const int d = kg * 16 + e;
            const float qv = h2f_u(qhb[rowoff + d]) + h2f_u(qlb[rowoff + d]);
            const int kofs = (d >> 3) * 128 + (d & 7);
            const float kv = h2f_u(ktb[kofs]) + h2f_u(ktb[1024 + kofs]);
            part = fmaf(qv, kv, part);
        }
        part += __shfl_xor(part, 16);
        part += __shfl_xor(part, 32);
        const float s = part * 0.125f;
        sc0 = (s > 0.f) ? s + pb0[r0w + lq] : -FLT_MAX;
    }
    if (lane < 16) s0s[w][lq] = sc0;

    // ---- gate + bias (C-layout: col = lane&15, row = kg*4+rg) ----
#pragma unroll
    for (int f = 0; f < 17; f++) {
        const int c = lo + f * 16 + lq;
        const bool cok = (c <= hi);
        f32x4 s4 = acc[f];
#pragma unroll
        for (int rg = 0; rg < 4; rg++) {
            const int r = r0w + kg * 4 + rg;
            const bool allowed = cok &&
                ((c == 0) || ((c >= r - WIN) && (c <= r + WIN)));
            const float s = s4[rg] * 0.125f;
            float sc = -FLT_MAX;
            if (allowed && s > 0.f)
                sc = s + pbp[(size_t)r * 272 + f * 16 + lq];
            s4[rg] = sc;
        }
        acc[f] = s4;
    }

    // ---- softmax (in-register, 16-lane butterflies) ----
    float s0r[4], mx[4];
#pragma unroll
    for (int rg = 0; rg < 4; rg++) {
        s0r[rg] = s0s[w][kg * 4 + rg];
        float m = s0r[rg];
#pragma unroll
        for (int f = 0; f < 17; f++) m = fmaxf(m, acc[f][rg]);
        m = fmaxf(m, __shfl_xor(m, 1));
        m = fmaxf(m, __shfl_xor(m, 2));
        m = fmaxf(m, __shfl_xor(m, 4));
        m = fmaxf(m, __shfl_xor(m, 8));
        mx[rg] = m;
    }

    float sum0 = 0.f, sum1 = 0.f, sum2 = 0.f, sum3 = 0.f;
#pragma unroll
    for (int f = 0; f < 17; f++) {
        const float p0_ = __expf(acc[f][0] - mx[0]); sum0 += p0_;
        const float p1_ = __expf(acc[f][1] - mx[1]); sum1 += p1_;
        const float p2_ = __expf(acc[f][2] - mx[2]); sum2 += p2_;
        const float p3_ = __expf(acc[f][3] - mx[3]); sum3 += p3_;
        Pl[w][kg * 4 + 0][f * 16 + lq] = f2h(p0_);
        Pl[w][kg * 4 + 1][f * 16 + lq] = f2h(p1_);
        Pl[w][kg * 4 + 2][f * 16 + lq] = f2h(p2_);
        Pl[w][kg * 4 + 3][f * 16 + lq] = f2h(p3_);
    }

    float inv[4], p0v[4];
    float sums[4] = {sum0, sum1, sum2, sum3};
#pragma unroll
    for (int rg = 0; rg < 4; rg++) {
        float s = sums[rg];
        s += __shfl_xor(s, 1);
        s += __shfl_xor(s, 2);
        s += __shfl_xor(s, 4);
        s += __shfl_xor(s, 8);
        const float p0 = has0 ? __expf(s0r[rg] - mx[rg]) : 0.f;
        p0v[rg] = p0;
        inv[rg] = 1.0f / (s + p0);
    }

    // ---- PV: A = P (LDS fp16), B = V^T tiled (dense wave reads) ----
    f32x4 pacc[4];
#pragma unroll
    for (int nf = 0; nf < 4; nf++) pacc[nf] = (f32x4){0.f, 0.f, 0.f, 0.f};
#pragma unroll
    for (int kf = 0; kf < 9; kf++) {
        const half8v pa = *(const half8v*)&Pl[w][lq][kf * 32 + kg * 8];
        int c0 = lo + kf * 32 + kg * 8;
        if (c0 > LL - 8) c0 = LL - 8;       // clamped spans have P==0
        const size_t vbase = (size_t)(c0 >> 5) * VTL_PER_TILE + (c0 & 31);
#pragma unroll
        for (int nf = 0; nf < 4; nf++) {
            const half8v vb =
                *(const half8v*)(vtb + vbase + (size_t)(nf * 16 + lq) * 32);
            pacc[nf] = __builtin_amdgcn_mfma_f32_16x16x32_f16(
                pa, vb, pacc[nf], 0, 0, 0);
        }
    }

    // ---- epilogue ----
#pragma unroll
    for (int nf = 0; nf < 4; nf++) {
        const int n = nf * 16 + lq;
        const float v0 = has0 ? h2f_u(vtb[(size_t)n * 32]) : 0.f;
#pragma unroll
        for (int rg = 0; rg < 4; rg++) {
            const int r = r0w + kg * 4 + rg;
            const float o = (pacc[nf][rg] + p0v[rg] * v0) * inv[rg];
            if (r != 0)
                attn16[((size_t)(b * LL + r)) * EE + h * DHD + n] = f2h(o);
        }
    }
}

// ---------------- out-proj: fp16 x fp16 MFMA, pipelined, f32 out -----------
__global__ __launch_bounds__(256) void gemm_o(
    const unsigned short* __restrict__ attn16, const unsigned short* __restrict__ woh,
    const float* __restrict__ bo, float* __restrict__ out)
{
    __shared__ unsigned short Ah[128 * 40], Bh[128 * 40];

    const int tid = threadIdx.x;
    const int w = tid >> 6, lane = tid & 63;
    const int wr = w >> 1, wc = w & 1;
    const int lr16 = lane & 15, kg = lane >> 4;
    const int row0 = blockIdx.y * 128, col0 = blockIdx.x * 128;
    const int srow = tid >> 1, shalf = tid & 1;
    const int sbase = srow * 40 + shalf * 16;

    const unsigned short* arow = attn16 + (size_t)(row0 + srow) * EE + shalf * 16;
    const unsigned short* brow = woh + (size_t)(col0 + srow) * EE + shalf * 16;

    f32x4 acc[4][4];
#pragma unroll
    for (int i = 0; i < 4; i++)
#pragma unroll
        for (int j = 0; j < 4; j++) acc[i][j] = (f32x4){0.f, 0.f, 0.f, 0.f};

    short8v ra0 = *(const short8v*)(arow + 0);
    short8v ra1 = *(const short8v*)(arow + 8);
    short8v rb0 = *(const short8v*)(brow + 0);
    short8v rb1 = *(const short8v*)(brow + 8);

    for (int t = 0; t < EE / 32; t++) {
        __syncthreads();
        *(short8v*)&Ah[sbase + 0] = ra0;
        *(short8v*)&Ah[sbase + 8] = ra1;
        *(short8v*)&Bh[sbase + 0] = rb0;
        *(short8v*)&Bh[sbase + 8] = rb1;
        __syncthreads();

        if (t + 1 < EE / 32) {
            const int k0 = (t + 1) * 32;
            ra0 = *(const short8v*)(arow + k0);
            ra1 = *(const short8v*)(arow + k0 + 8);
            rb0 = *(const short8v*)(brow + k0);
            rb1 = *(const short8v*)(brow + k0 + 8);
        }

        half8v af[4], bf[4];
#pragma unroll
        for (int mr = 0; mr < 4; mr++)
            af[mr] = *(const half8v*)&Ah[(wr*64 + mr*16 + lr16)*40 + kg*8];
#pragma unroll
        for (int nr = 0; nr < 4; nr++)
            bf[nr] = *(const half8v*)&Bh[(wc*64 + nr*16 + lr16)*40 + kg*8];
#pragma unroll
        for (int mr = 0; mr < 4; mr++)
#pragma unroll
            for (int nr = 0; nr < 4; nr++)
                acc[mr][nr] = __builtin_amdgcn_mfma_f32_16x16x32_f16(
                    af[mr], bf[nr], acc[mr][nr], 0, 0, 0);
    }

#pragma unroll
    for (int mr = 0; mr < 4; mr++) {
#pragma unroll
        for (int nr = 0; nr < 4; nr++) {
            const int n = col0 + wc * 64 + nr * 16 + lr16;
            const float bb = bo[n];
#pragma unroll
            for (int j = 0; j < 4; j++) {
                const int m = row0 + wr * 64 + mr * 16 + kg * 4 + j;
                out[(size_t)m * EE + n] = acc[mr][nr][j] + bb;
            }
        }
    }
}

extern "C" void kernel_launch(void* const* d_in, const int* in_sizes, int n_in,
                              void* d_out, int out_size, void* d_ws, size_t ws_size,
                              hipStream_t stream) {
    const float* x        = (const float*)d_in[0];
    const float* pos_bias = (const float*)d_in[1];
    const float* Wq = (const float*)d_in[2];
    const float* bq = (const float*)d_in[3];
    const float* Wk = (const float*)d_in[4];
    const float* bk = (const float*)d_in[5];
    const float* Wv = (const float*)d_in[6];
    const float* bv = (const float*)d_in[7];
    const float* Wo = (const float*)d_in[8];
    const float* bo = (const float*)d_in[9];
    float* out = (float*)d_out;

    const size_t M1 = (size_t)1024 * 1024;         // 1M u16 units
    unsigned short* u = (unsigned short*)d_ws;
    unsigned short* xh  = u;                        // 4M
    unsigned short* xl  = u + 4 * M1;               // 4M (dead after gemm_qkv)
    unsigned short* wqh = u + 8 * M1;               // 1M each
    unsigned short* wql = u + 9 * M1;
    unsigned short* wkh = u + 10 * M1;
    unsigned short* wkl = u + 11 * M1;
    unsigned short* qhi = u + 12 * M1;              // 4M each
    unsigned short* qlo = u + 16 * M1;
    unsigned short* ktl = u + 20 * M1;              // 8M (tiled K hi+lo)
    unsigned short* vtl = u + 28 * M1;              // 4M (tiled V) -> 32M u16
    unsigned short* attn16 = xh;                    // reuse (xh dead post-QKV)
    float* pbp = (float*)(u + 4 * M1);              // reuse xl AFTER gemm_qkv
    float* pb0 = pbp + (size_t)2048 * 272;          // + 2048 f32
    unsigned short* woh = u + 7 * M1;               // xl region tail: 1M u16

    prep_split<<<dim3(2048), 256, 0, stream>>>(x, Wq, Wk, xh, xl,
                                               wqh, wql, wkh, wkl);
    gemm_qkv<<<dim3(1024), 256, 0, stream>>>(xh, xl, wqh, wql, wkh, wkl,
                                             Wv, bq, bk, bv,
                                             qhi, qlo, ktl, vtl);
    pack_bias<<<dim3(2048), 256, 0, stream>>>(pos_bias, pbp, pb0, Wo, woh);
    attn_mfma<<<dim3(1056), 256, 0, stream>>>(qhi, qlo, ktl, vtl,
                                              pos_bias, pbp, pb0, attn16);
    gemm_o<<<dim3(8, 32), 256, 0, stream>>>(attn16, woh, bo, out);
}